// Round 1
// baseline (359.266 us; speedup 1.0000x reference)
//
#include <hip/hip_runtime.h>

#define BB 16
#define CC 128
#define HH 64
#define WW 64
#define OO 128
#define KK 4
#define RR 32
// per-k kernel bank size in floats: O*C*3*3
#define KBANK (OO*CC*9)

// ---------------- kernel 1: global average pool ----------------
// grid = B*C blocks, 256 threads; each block reduces one (b,c) plane of 4096 floats
__global__ void pool_kernel(const float* __restrict__ x, float* __restrict__ pooled) {
    int bc = blockIdx.x;
    const float4* p4 = (const float4*)(x + (size_t)bc * (HH * WW));
    int t = threadIdx.x;
    float s = 0.f;
    #pragma unroll
    for (int i = 0; i < 4; ++i) {
        float4 v = p4[t + i * 256];
        s += v.x + v.y + v.z + v.w;
    }
    #pragma unroll
    for (int off = 32; off > 0; off >>= 1) s += __shfl_down(s, off, 64);
    __shared__ float ls[4];
    if ((t & 63) == 0) ls[t >> 6] = s;
    __syncthreads();
    if (t == 0) {
        float tot = ls[0] + ls[1] + ls[2] + ls[3];
        pooled[bc] = tot * (1.0f / (HH * WW));
    }
}

// ---------------- kernel 2: SE MLP + softmax ----------------
// single block, 512 threads: thread = b*32 + r computes h[b][r]
__global__ void attn_kernel(const float* __restrict__ pooled,
                            const float* __restrict__ w1, const float* __restrict__ b1,
                            const float* __restrict__ w2, const float* __restrict__ b2,
                            float* __restrict__ attn) {
    __shared__ float hs[BB][RR];
    __shared__ float lg[BB][KK];
    int t = threadIdx.x;
    int b = t >> 5, r = t & 31;
    float acc = b1[r];
    for (int c = 0; c < CC; ++c) acc += pooled[b * CC + c] * w1[r * CC + c];
    hs[b][r] = fmaxf(acc, 0.f);
    __syncthreads();
    if (t < BB * KK) {
        int bb = t >> 2, k = t & 3;
        float a = b2[k];
        #pragma unroll
        for (int rr = 0; rr < RR; ++rr) a += hs[bb][rr] * w2[k * RR + rr];
        lg[bb][k] = a;
    }
    __syncthreads();
    if (t < BB) {
        float l0 = lg[t][0], l1 = lg[t][1], l2 = lg[t][2], l3 = lg[t][3];
        float m = fmaxf(fmaxf(l0, l1), fmaxf(l2, l3));
        float e0 = expf(l0 - m), e1 = expf(l1 - m), e2 = expf(l2 - m), e3 = expf(l3 - m);
        float inv = 1.f / (e0 + e1 + e2 + e3);
        attn[t * KK + 0] = e0 * inv;
        attn[t * KK + 1] = e1 * inv;
        attn[t * KK + 2] = e2 * inv;
        attn[t * KK + 3] = e3 * inv;
    }
}

// ---------------- kernel 3: mix kernel bank with per-sample attention ----------------
// wmix[b][o][c][3][3] = sum_k attn[b][k] * kernels[k][o][c][3][3]
// grid (144, 16), 256 threads, one float4 per thread (KBANK/4 = 36864 float4 per b)
__global__ void mix_kernel(const float* __restrict__ kernels,
                           const float* __restrict__ attn,
                           float* __restrict__ wmix) {
    int b = blockIdx.y;
    int i = blockIdx.x * 256 + threadIdx.x;   // < 36864
    float a0 = attn[b * KK + 0], a1 = attn[b * KK + 1];
    float a2 = attn[b * KK + 2], a3 = attn[b * KK + 3];
    const float4* k4 = (const float4*)kernels;
    float4 v0 = k4[i];
    float4 v1 = k4[(KBANK / 4) + i];
    float4 v2 = k4[2 * (KBANK / 4) + i];
    float4 v3 = k4[3 * (KBANK / 4) + i];
    float4 o;
    o.x = a0 * v0.x + a1 * v1.x + a2 * v2.x + a3 * v3.x;
    o.y = a0 * v0.y + a1 * v1.y + a2 * v2.y + a3 * v3.y;
    o.z = a0 * v0.z + a1 * v1.z + a2 * v2.z + a3 * v3.z;
    o.w = a0 * v0.w + a1 * v1.w + a2 * v2.w + a3 * v3.w;
    ((float4*)wmix)[(size_t)b * (KBANK / 4) + i] = o;
}

// ---------------- kernel 4: per-sample 3x3 conv (direct, fp32) ----------------
// grid (O/8, H/16, B), 256 threads. Block: fixed b, 8 output channels, 16x64 tile.
// thread t: w = t&63, hq = t>>6 -> output rows h0 + hq*4 + {0..3}
#define OPB 8
__global__ __launch_bounds__(256) void conv_kernel(const float* __restrict__ x,
                            const float* __restrict__ wmix,
                            float* __restrict__ out) {
    __shared__ float xs[18][66];
    int b = blockIdx.z;
    int o0 = blockIdx.x * OPB;
    int h0 = blockIdx.y * 16;
    int t = threadIdx.x;
    int w = t & 63, hq = t >> 6;

    float acc[OPB][4];
    #pragma unroll
    for (int oo = 0; oo < OPB; ++oo)
        #pragma unroll
        for (int q = 0; q < 4; ++q) acc[oo][q] = 0.f;

    for (int c = 0; c < CC; ++c) {
        __syncthreads();
        // stage 18x66 halo tile for channel c (zero-padded)
        #pragma unroll
        for (int j = 0; j < 5; ++j) {
            int e = t + j * 256;
            if (e < 18 * 66) {
                int row = e / 66, col = e - row * 66;
                int hh = h0 - 1 + row, ww = col - 1;
                float v = 0.f;
                if (hh >= 0 && hh < HH && ww >= 0 && ww < WW)
                    v = x[((size_t)(b * CC + c) * HH + hh) * WW + ww];
                xs[row][col] = v;
            }
        }
        __syncthreads();
        // load 6x3 window for this thread's 4 rows
        float win[6][3];
        #pragma unroll
        for (int rr = 0; rr < 6; ++rr)
            #pragma unroll
            for (int cc2 = 0; cc2 < 3; ++cc2)
                win[rr][cc2] = xs[hq * 4 + rr][w + cc2];
        #pragma unroll
        for (int oo = 0; oo < OPB; ++oo) {
            // wave-uniform address -> scalar loads
            const float* wp = wmix + ((size_t)(b * OO + o0 + oo) * CC + c) * 9;
            float w00 = wp[0], w01 = wp[1], w02 = wp[2];
            float w10 = wp[3], w11 = wp[4], w12 = wp[5];
            float w20 = wp[6], w21 = wp[7], w22 = wp[8];
            #pragma unroll
            for (int q = 0; q < 4; ++q) {
                float s = acc[oo][q];
                s += win[q + 0][0] * w00 + win[q + 0][1] * w01 + win[q + 0][2] * w02;
                s += win[q + 1][0] * w10 + win[q + 1][1] * w11 + win[q + 1][2] * w12;
                s += win[q + 2][0] * w20 + win[q + 2][1] * w21 + win[q + 2][2] * w22;
                acc[oo][q] = s;
            }
        }
    }
    // write out
    #pragma unroll
    for (int oo = 0; oo < OPB; ++oo)
        #pragma unroll
        for (int q = 0; q < 4; ++q)
            out[(((size_t)b * OO + o0 + oo) * HH + h0 + hq * 4 + q) * WW + w] = acc[oo][q];
}

extern "C" void kernel_launch(void* const* d_in, const int* in_sizes, int n_in,
                              void* d_out, int out_size, void* d_ws, size_t ws_size,
                              hipStream_t stream) {
    const float* x       = (const float*)d_in[0];
    const float* w1      = (const float*)d_in[1];
    const float* b1      = (const float*)d_in[2];
    const float* w2      = (const float*)d_in[3];
    const float* b2      = (const float*)d_in[4];
    const float* kernels = (const float*)d_in[5];
    float* out = (float*)d_out;

    // workspace layout (floats): pooled[2048] | attn[64] | wmix[16*147456]
    float* pooled = (float*)d_ws;
    float* attn   = pooled + BB * CC;
    float* wmix   = attn + BB * KK;

    pool_kernel<<<BB * CC, 256, 0, stream>>>(x, pooled);
    attn_kernel<<<1, 512, 0, stream>>>(pooled, w1, b1, w2, b2, attn);
    mix_kernel<<<dim3(KBANK / 4 / 256, BB), 256, 0, stream>>>(kernels, attn, wmix);
    conv_kernel<<<dim3(OO / OPB, HH / 16, BB), 256, 0, stream>>>(x, wmix, out);
}

// Round 2
// 84.995 us; speedup vs baseline: 4.2269x; 4.2269x over previous
//
#include <hip/hip_runtime.h>

#define BB 16
#define CC 128
#define HH 64
#define WW 64
#define OO 128
#define KK 4
#define RR 32
#define KTOT 1152  // 9 * 128

typedef short v8s __attribute__((ext_vector_type(8)));
typedef float v4f __attribute__((ext_vector_type(4)));

__device__ __forceinline__ unsigned short f2bf(float f) {
    unsigned u = __builtin_bit_cast(unsigned, f);
    u += 0x7fffu + ((u >> 16) & 1u);
    return (unsigned short)(u >> 16);
}

// ---------------- kernel 1: global average pool (fp32, exact) ----------------
__global__ void pool_kernel(const float* __restrict__ x, float* __restrict__ pooled) {
    int bc = blockIdx.x;
    const float4* p4 = (const float4*)(x + (size_t)bc * (HH * WW));
    int t = threadIdx.x;
    float s = 0.f;
    #pragma unroll
    for (int i = 0; i < 4; ++i) {
        float4 v = p4[t + i * 256];
        s += v.x + v.y + v.z + v.w;
    }
    #pragma unroll
    for (int off = 32; off > 0; off >>= 1) s += __shfl_down(s, off, 64);
    __shared__ float ls[4];
    if ((t & 63) == 0) ls[t >> 6] = s;
    __syncthreads();
    if (t == 0) pooled[bc] = (ls[0] + ls[1] + ls[2] + ls[3]) * (1.0f / (HH * WW));
}

// ---------------- kernel 2: SE MLP + softmax ----------------
__global__ void attn_kernel(const float* __restrict__ pooled,
                            const float* __restrict__ w1, const float* __restrict__ b1,
                            const float* __restrict__ w2, const float* __restrict__ b2,
                            float* __restrict__ attn) {
    __shared__ float hs[BB][RR];
    __shared__ float lg[BB][KK];
    int t = threadIdx.x;
    int b = t >> 5, r = t & 31;
    float acc = b1[r];
    for (int c = 0; c < CC; ++c) acc += pooled[b * CC + c] * w1[r * CC + c];
    hs[b][r] = fmaxf(acc, 0.f);
    __syncthreads();
    if (t < BB * KK) {
        int bb = t >> 2, k = t & 3;
        float a = b2[k];
        #pragma unroll
        for (int rr = 0; rr < RR; ++rr) a += hs[bb][rr] * w2[k * RR + rr];
        lg[bb][k] = a;
    }
    __syncthreads();
    if (t < BB) {
        float l0 = lg[t][0], l1 = lg[t][1], l2 = lg[t][2], l3 = lg[t][3];
        float m = fmaxf(fmaxf(l0, l1), fmaxf(l2, l3));
        float e0 = expf(l0 - m), e1 = expf(l1 - m), e2 = expf(l2 - m), e3 = expf(l3 - m);
        float inv = 1.f / (e0 + e1 + e2 + e3);
        attn[t * KK + 0] = e0 * inv;
        attn[t * KK + 1] = e1 * inv;
        attn[t * KK + 2] = e2 * inv;
        attn[t * KK + 3] = e3 * inv;
    }
}

// ---------------- kernel 3: mix bank -> bf16 A-matrix [b][o][tap][c] ----------------
__global__ void mix_kernel(const float* __restrict__ kernels,
                           const float* __restrict__ attn,
                           unsigned short* __restrict__ wmixb) {
    int b = blockIdx.y, o = blockIdx.x;
    float a0 = attn[b * 4 + 0], a1 = attn[b * 4 + 1];
    float a2 = attn[b * 4 + 2], a3 = attn[b * 4 + 3];
    const size_t KB = (size_t)OO * CC * 9;
    const float* k0 = kernels + (size_t)o * CC * 9;
    unsigned short* wp = wmixb + ((size_t)b * OO + o) * KTOT;
    for (int i = threadIdx.x; i < KTOT; i += 256) {
        int tap = i >> 7, c = i & 127;
        size_t off = (size_t)c * 9 + tap;
        float v = a0 * k0[off] + a1 * k0[KB + off] + a2 * k0[2 * KB + off] + a3 * k0[3 * KB + off];
        wp[i] = f2bf(v);
    }
}

// ---------------- kernel 4: x fp32 NCHW -> bf16 NHWC ----------------
__global__ void convert_kernel(const float* __restrict__ x, unsigned short* __restrict__ xb) {
    int idx = blockIdx.x * 256 + threadIdx.x;   // (b, g, p), p fastest -> coalesced reads
    int p = idx & 4095;
    int g = (idx >> 12) & 15;
    int b = idx >> 16;
    const float* xp = x + ((size_t)(b * CC + g * 8)) * 4096 + p;
    v8s v;
    #pragma unroll
    for (int j = 0; j < 8; ++j) v[j] = (short)f2bf(xp[(size_t)j * 4096]);
    *(v8s*)(xb + ((size_t)(b * 4096 + p)) * CC + g * 8) = v;
}

// ---------------- kernel 5: implicit-GEMM conv, bf16 MFMA ----------------
// block = (sample b, 2 output rows). M=128 (all O), N=128 (2 rows x 64 cols).
// 4 waves: wm in {0,1} (64 o-rows), wn in {0,1} (which output row).
// x tile in LDS: rows r0-1..r0+2, cols -1..64, 64 channels per phase, XOR-swizzled.
#define MFMA16(acc, va, vb) \
    asm volatile("v_mfma_f32_16x16x32_bf16 %0, %1, %2, %0" : "+v"(acc) : "v"(va), "v"(vb))

__global__ __launch_bounds__(256) void conv_kernel(
        const unsigned short* __restrict__ xb,
        const unsigned short* __restrict__ wmixb,
        float* __restrict__ out) {
    __shared__ unsigned short xs[4 * 66 * 64];   // 33792 B
    int bid = blockIdx.x;
    int b = bid >> 5;
    int r0 = (bid & 31) * 2;
    int t = threadIdx.x;
    int lane = t & 63, wid = t >> 6;
    int wm = wid & 1, wn = wid >> 1;

    v4f acc[4][4];
    #pragma unroll
    for (int i = 0; i < 4; ++i)
        #pragma unroll
        for (int j = 0; j < 4; ++j) acc[i][j] = (v4f)0.f;

    // A base: lane holds W[o = wm*64 + mf*16 + (lane&15)][k0 + (lane>>4)*8 .. +7]
    const unsigned short* wbase =
        wmixb + ((size_t)b * OO + wm * 64 + (lane & 15)) * KTOT + ((lane >> 4) << 3);

    #pragma unroll
    for (int ch = 0; ch < 2; ++ch) {
        __syncthreads();
        // stage 4 rows x 66 cols x 64 ch (this phase's channel half), zero-pad halo
        for (int e = t; e < 4 * 66 * 8; e += 256) {
            int g = e & 7;
            int pc = e >> 3;
            int col = pc % 66;
            int row = pc / 66;
            int h = r0 - 1 + row;
            int w = col - 1;
            v8s v = (v8s)0;
            if (h >= 0 && h < HH && w >= 0 && w < WW)
                v = *(const v8s*)(xb + ((size_t)(b * 4096 + h * 64 + w)) * CC + ch * 64 + g * 8);
            int off = ((row * 66 + col) * 128 + g * 16) ^ ((col & 7) << 4);
            *(v8s*)((char*)xs + off) = v;
        }
        __syncthreads();

        v8s areg[3][4], bfr[4];
        // prefetch A for ks=0,1 (depth-2 pipeline over ~250cyc L2 latency)
        #pragma unroll
        for (int pf = 0; pf < 2; ++pf) {
            int tap = pf >> 1, c0l = (pf & 1) << 5;
            const unsigned short* p = wbase + tap * 128 + ch * 64 + c0l;
            #pragma unroll
            for (int mf = 0; mf < 4; ++mf) areg[pf][mf] = *(const v8s*)(p + (size_t)mf * 16 * KTOT);
        }
        #pragma unroll
        for (int ks = 0; ks < 18; ++ks) {
            const int cur = ks % 3;
            const int nxt = (ks + 2) % 3;
            if (ks < 16) {
                int ks2 = ks + 2;
                int tap = ks2 >> 1, c0l = (ks2 & 1) << 5;
                const unsigned short* p = wbase + tap * 128 + ch * 64 + c0l;
                #pragma unroll
                for (int mf = 0; mf < 4; ++mf) areg[nxt][mf] = *(const v8s*)(p + (size_t)mf * 16 * KTOT);
            }
            int tap = ks >> 1, c0l = (ks & 1) << 5;
            int dy = tap / 3, dx = tap % 3;
            int row = wn + dy;
            int cbyte = (c0l + ((lane >> 4) << 3)) * 2;
            #pragma unroll
            for (int nf = 0; nf < 4; ++nf) {
                int col = nf * 16 + (lane & 15) + dx;
                int off = ((row * 66 + col) * 128 + cbyte) ^ ((col & 7) << 4);
                bfr[nf] = *(const v8s*)((const char*)xs + off);
            }
            #pragma unroll
            for (int mf = 0; mf < 4; ++mf)
                #pragma unroll
                for (int nf = 0; nf < 4; ++nf)
                    MFMA16(acc[mf][nf], areg[cur][mf], bfr[nf]);
        }
    }
    asm volatile("s_nop 7\ns_nop 7" ::: );

    // epilogue: C/D layout col = lane&15 (pixel), row = (lane>>4)*4 + j (o)
    int r = r0 + wn;
    #pragma unroll
    for (int mf = 0; mf < 4; ++mf) {
        int o = wm * 64 + mf * 16 + ((lane >> 4) << 2);
        #pragma unroll
        for (int j = 0; j < 4; ++j) {
            float* op = out + (((size_t)(b * OO + o + j)) * HH + r) * WW;
            #pragma unroll
            for (int nf = 0; nf < 4; ++nf)
                op[nf * 16 + (lane & 15)] = acc[mf][nf][j];
        }
    }
}

extern "C" void kernel_launch(void* const* d_in, const int* in_sizes, int n_in,
                              void* d_out, int out_size, void* d_ws, size_t ws_size,
                              hipStream_t stream) {
    const float* x       = (const float*)d_in[0];
    const float* w1      = (const float*)d_in[1];
    const float* b1      = (const float*)d_in[2];
    const float* w2      = (const float*)d_in[3];
    const float* b2      = (const float*)d_in[4];
    const float* kernels = (const float*)d_in[5];
    float* out = (float*)d_out;

    // ws layout: pooled[2048] f32 | attn[64] f32 | xb[16*4096*128] bf16 | wmixb[16*128*1152] bf16
    float* pooled = (float*)d_ws;
    float* attnp  = pooled + BB * CC;
    unsigned short* xb    = (unsigned short*)(attnp + BB * KK);
    unsigned short* wmixb = xb + (size_t)BB * 4096 * CC;

    convert_kernel<<<BB * 16 * 4096 / 256, 256, 0, stream>>>(x, xb);
    pool_kernel<<<BB * CC, 256, 0, stream>>>(x, pooled);
    attn_kernel<<<1, 512, 0, stream>>>(pooled, w1, b1, w2, b2, attnp);
    mix_kernel<<<dim3(OO, BB), 256, 0, stream>>>(kernels, attnp, wmixb);
    conv_kernel<<<BB * 32, 256, 0, stream>>>(xb, wmixb, out);
}

// Round 3
// 74.507 us; speedup vs baseline: 4.8219x; 1.1408x over previous
//
#include <hip/hip_runtime.h>

#define BB 16
#define CC 128
#define HH 64
#define WW 64
#define OO 128
#define KK 4
#define RR 32
#define KTOT 1152  // 9 * 128

typedef short v8s __attribute__((ext_vector_type(8)));
typedef float v4f __attribute__((ext_vector_type(4)));

__device__ __forceinline__ unsigned short f2bf(float f) {
    unsigned u = __builtin_bit_cast(unsigned, f);
    u += 0x7fffu + ((u >> 16) & 1u);
    return (unsigned short)(u >> 16);
}

// ---------------- kernel 1: convert fp32 NCHW -> bf16 NHWC, fused global-avg-pool ----------------
// grid 4096 x 256. Block covers (b, g=8-ch group, 256 pixels). Partial sums -> atomicAdd.
__global__ __launch_bounds__(256) void convert_pool_kernel(const float* __restrict__ x,
        unsigned short* __restrict__ xb, float* __restrict__ pooled) {
    int idx = blockIdx.x * 256 + threadIdx.x;
    int p = idx & 4095;
    int g = (idx >> 12) & 15;
    int b = idx >> 16;
    const float* xp = x + ((size_t)(b * CC + g * 8)) * 4096 + p;
    float vals[8];
    v8s v;
    #pragma unroll
    for (int j = 0; j < 8; ++j) {
        vals[j] = xp[(size_t)j * 4096];
        v[j] = (short)f2bf(vals[j]);
    }
    *(v8s*)(xb + ((size_t)(b * 4096 + p)) * CC + g * 8) = v;

    __shared__ float ls[4][8];
    int lane = threadIdx.x & 63, wv = threadIdx.x >> 6;
    #pragma unroll
    for (int j = 0; j < 8; ++j) {
        float s = vals[j];
        #pragma unroll
        for (int off = 32; off > 0; off >>= 1) s += __shfl_down(s, off, 64);
        if (lane == 0) ls[wv][j] = s;
    }
    __syncthreads();
    if (threadIdx.x < 8) {
        float s = ls[0][threadIdx.x] + ls[1][threadIdx.x] + ls[2][threadIdx.x] + ls[3][threadIdx.x];
        atomicAdd(&pooled[b * CC + g * 8 + threadIdx.x], s);
    }
}

// ---------------- kernel 2: fused SE-MLP + softmax + bank mix -> bf16 A-matrix [b][o][tap][c] ----
// grid (O, B) x 256. Each block recomputes the tiny attention for its b (w1/w2 L2-hot),
// then mixes the 4 banks reading CONTIGUOUS (c*9+tap) order, transposing via LDS.
__global__ __launch_bounds__(256) void mix_kernel(const float* __restrict__ kernels,
        const float* __restrict__ pooled,
        const float* __restrict__ w1, const float* __restrict__ b1,
        const float* __restrict__ w2, const float* __restrict__ b2,
        unsigned short* __restrict__ wmixb) {
    const int b = blockIdx.y, o = blockIdx.x;
    const int t = threadIdx.x;
    __shared__ float hs[RR];
    __shared__ float lgs[KK];
    __shared__ float attns[KK];
    __shared__ unsigned short ws[KTOT];

    if (t < RR) {
        float acc = b1[t];
        const float* pr = pooled + b * CC;
        const float* wr = w1 + t * CC;
        for (int c = 0; c < CC; ++c) acc += (pr[c] * (1.0f / 4096.0f)) * wr[c];
        hs[t] = fmaxf(acc, 0.f);
    }
    __syncthreads();
    if (t < KK) {
        float a = b2[t];
        #pragma unroll
        for (int r = 0; r < RR; ++r) a += hs[r] * w2[t * RR + r];
        lgs[t] = a;
    }
    __syncthreads();
    if (t == 0) {
        float m = fmaxf(fmaxf(lgs[0], lgs[1]), fmaxf(lgs[2], lgs[3]));
        float e0 = expf(lgs[0] - m), e1 = expf(lgs[1] - m);
        float e2 = expf(lgs[2] - m), e3 = expf(lgs[3] - m);
        float inv = 1.f / (e0 + e1 + e2 + e3);
        attns[0] = e0 * inv; attns[1] = e1 * inv; attns[2] = e2 * inv; attns[3] = e3 * inv;
    }
    __syncthreads();
    float a0 = attns[0], a1 = attns[1], a2 = attns[2], a3 = attns[3];

    const size_t KB = (size_t)OO * KTOT;
    const float* k0 = kernels + (size_t)o * KTOT;
    for (int ii = t; ii < KTOT; ii += 256) {
        int c = ii / 9, tap = ii - c * 9;
        float v = a0 * k0[ii] + a1 * k0[KB + ii] + a2 * k0[2 * KB + ii] + a3 * k0[3 * KB + ii];
        ws[tap * 128 + c] = f2bf(v);
    }
    __syncthreads();
    v8s* wp8 = (v8s*)(wmixb + ((size_t)b * OO + o) * KTOT);
    const v8s* ls8 = (const v8s*)ws;
    for (int ii = t; ii < KTOT / 8; ii += 256) wp8[ii] = ls8[ii];
}

// ---------------- kernel 3: implicit-GEMM conv, bf16 MFMA ----------------
// grid 256 x 512. Block = (b, 4 output rows). 8 waves: wm in {0,1} x wn in {0..3},
// wave tile M64 x N64 (one output row). x tile [6 rows][66 cols][64 ch/phase] in LDS,
// XOR-swizzled; A (weights) streamed from global with 2-deep prefetch; B ping-pong 1-deep.
#define MFMA16(acc, va, vb) \
    asm volatile("v_mfma_f32_16x16x32_bf16 %0, %1, %2, %0" : "+v"(acc) : "v"(va), "v"(vb))

#define LOADB(dst, ks_) { \
    const int tap_ = (ks_) >> 1; \
    const int dy_ = tap_ / 3, dx_ = tap_ % 3; \
    const int row_ = wn + dy_; \
    const int cbyte_ = ((ks_) & 1) * 64 + ((lane >> 4) << 4); \
    _Pragma("unroll") \
    for (int nf = 0; nf < 4; ++nf) { \
        int col_ = nf * 16 + (lane & 15) + dx_; \
        int off_ = ((row_ * 66 + col_) * 128 + cbyte_) ^ ((col_ & 7) << 4); \
        dst[nf] = *(const v8s*)((const char*)xs + off_); \
    } }

__global__ __launch_bounds__(512) void conv_kernel(
        const unsigned short* __restrict__ xb,
        const unsigned short* __restrict__ wmixb,
        float* __restrict__ out) {
    __shared__ unsigned short xs[6 * 66 * 64];   // 50688 B
    int bid = blockIdx.x;
    // XCD-aware decode: XCD x (= bid%8 by default round-robin) hosts b in {2x, 2x+1}
    int j = bid >> 3;
    int b = (bid & 7) * 2 + (j >> 4);
    int r0 = (j & 15) * 4;
    int t = threadIdx.x;
    int lane = t & 63, wid = t >> 6;
    int wm = wid & 1, wn = wid >> 1;   // wn in 0..3

    v4f acc[4][4];
    #pragma unroll
    for (int i = 0; i < 4; ++i)
        #pragma unroll
        for (int jj = 0; jj < 4; ++jj) acc[i][jj] = (v4f)0.f;

    // lane holds W[o = wm*64 + mf*16 + (lane&15)][k + (lane>>4)*8 .. +7]
    const unsigned short* wbase =
        wmixb + ((size_t)b * OO + wm * 64 + (lane & 15)) * KTOT + ((lane >> 4) << 3);

    v8s areg[3][4], bf[2][4];

    #pragma unroll
    for (int ch = 0; ch < 2; ++ch) {
        // A prologue for ks=0,1 (global loads; latency hidden under staging)
        #pragma unroll
        for (int pf = 0; pf < 2; ++pf) {
            const unsigned short* pA = wbase + ch * 64 + (pf & 1) * 32;   // tap 0
            #pragma unroll
            for (int mf = 0; mf < 4; ++mf)
                areg[pf][mf] = *(const v8s*)(pA + (size_t)mf * 16 * KTOT);
        }
        __syncthreads();
        // stage [6][66][64ch of this phase], zero-padded halo, XOR-swizzled
        for (int e = t; e < 6 * 66 * 8; e += 512) {
            int g = e & 7;
            int pc = e >> 3;
            int col = pc % 66;
            int row = pc / 66;
            int h = r0 - 1 + row, w = col - 1;
            v8s v = (v8s)0;
            if (h >= 0 && h < HH && w >= 0 && w < WW)
                v = *(const v8s*)(xb + ((size_t)(b * 4096 + h * 64 + w)) * CC + ch * 64 + g * 8);
            int off = ((row * 66 + col) * 128 + g * 16) ^ ((col & 7) << 4);
            *(v8s*)((char*)xs + off) = v;
        }
        __syncthreads();

        LOADB(bf[0], 0);
        #pragma unroll
        for (int ks = 0; ks < 18; ++ks) {
            const int cur = ks & 1, nxt = cur ^ 1;
            if (ks < 17) LOADB(bf[nxt], ks + 1);
            if (ks < 16) {
                const int ks2 = ks + 2;
                const unsigned short* pA = wbase + (ks2 >> 1) * 128 + ch * 64 + (ks2 & 1) * 32;
                #pragma unroll
                for (int mf = 0; mf < 4; ++mf)
                    areg[ks2 % 3][mf] = *(const v8s*)(pA + (size_t)mf * 16 * KTOT);
            }
            #pragma unroll
            for (int mf = 0; mf < 4; ++mf)
                #pragma unroll
                for (int nf = 0; nf < 4; ++nf)
                    MFMA16(acc[mf][nf], areg[ks % 3][mf], bf[cur][nf]);
        }
    }
    asm volatile("s_nop 7\ns_nop 7" ::: );

    // epilogue: C/D layout col = lane&15 (pixel), row = (lane>>4)*4 + jj (o)
    int r = r0 + wn;
    #pragma unroll
    for (int mf = 0; mf < 4; ++mf) {
        int o = wm * 64 + mf * 16 + ((lane >> 4) << 2);
        #pragma unroll
        for (int jj = 0; jj < 4; ++jj) {
            float* op = out + (((size_t)(b * OO + o + jj)) * HH + r) * WW;
            #pragma unroll
            for (int nf = 0; nf < 4; ++nf)
                op[nf * 16 + (lane & 15)] = acc[mf][nf][jj];
        }
    }
}

extern "C" void kernel_launch(void* const* d_in, const int* in_sizes, int n_in,
                              void* d_out, int out_size, void* d_ws, size_t ws_size,
                              hipStream_t stream) {
    const float* x       = (const float*)d_in[0];
    const float* w1      = (const float*)d_in[1];
    const float* b1      = (const float*)d_in[2];
    const float* w2      = (const float*)d_in[3];
    const float* b2      = (const float*)d_in[4];
    const float* kernels = (const float*)d_in[5];
    float* out = (float*)d_out;

    // ws layout: pooled[2048] f32 | xb[16*4096*128] bf16 | wmixb[16*128*1152] bf16
    float* pooled = (float*)d_ws;
    unsigned short* xb    = (unsigned short*)(pooled + BB * CC);
    unsigned short* wmixb = xb + (size_t)BB * 4096 * CC;

    hipMemsetAsync(pooled, 0, BB * CC * sizeof(float), stream);
    convert_pool_kernel<<<4096, 256, 0, stream>>>(x, xb, pooled);
    mix_kernel<<<dim3(OO, BB), 256, 0, stream>>>(kernels, pooled, w1, b1, w2, b2, wmixb);
    conv_kernel<<<256, 512, 0, stream>>>(xb, wmixb, out);
}

// Round 4
// 67.120 us; speedup vs baseline: 5.3526x; 1.1101x over previous
//
#include <hip/hip_runtime.h>

#define BB 16
#define CC 128
#define HH 64
#define WW 64
#define OO 128
#define KK 4
#define RR 32
#define KTOT 1152          // 9 * 128
#define NT 36              // K-steps of 32
#define XP 66              // padded spatial dim

typedef short v8s __attribute__((ext_vector_type(8)));
typedef float v4f __attribute__((ext_vector_type(4)));

__device__ __forceinline__ unsigned short f2bf(float f) {
    unsigned u = __builtin_bit_cast(unsigned, f);
    u += 0x7fffu + ((u >> 16) & 1u);
    return (unsigned short)(u >> 16);
}

// async global->LDS, 16B per lane; LDS dest is wave-uniform base + lane*16
__device__ __forceinline__ void gl16(const unsigned short* g, unsigned short* l) {
    __builtin_amdgcn_global_load_lds(
        (const __attribute__((address_space(1))) unsigned int*)g,
        (__attribute__((address_space(3))) unsigned int*)l, 16, 0, 0);
}

// ---------------- kernel 0: zero the halo border of padded xb ----------------
__global__ void border_kernel(unsigned short* __restrict__ xbp) {
    int i = blockIdx.x * 256 + threadIdx.x;   // [0, 4160) cells*16
    if (i >= 4160) return;
    int b = blockIdx.y;
    int cell = i >> 4, wi = i & 15;
    int r, c;
    if (cell < 66)       { r = 0;              c = cell; }
    else if (cell < 132) { r = 65;             c = cell - 66; }
    else if (cell < 196) { r = cell - 132 + 1; c = 0; }
    else                 { r = cell - 196 + 1; c = 65; }
    *(v8s*)(xbp + ((size_t)((b * XP + r) * XP + c)) * CC + wi * 8) = (v8s)0;
}

// ---------------- kernel 1: convert fp32 NCHW -> bf16 padded NHWC + fused avg-pool ----------------
__global__ __launch_bounds__(256) void convert_pool_kernel(const float* __restrict__ x,
        unsigned short* __restrict__ xbp, float* __restrict__ pooled) {
    int idx = blockIdx.x * 256 + threadIdx.x;
    int p = idx & 4095;
    int g = (idx >> 12) & 15;
    int b = idx >> 16;
    const float* xp = x + ((size_t)(b * CC + g * 8)) * 4096 + p;
    float vals[8];
    v8s v;
    #pragma unroll
    for (int j = 0; j < 8; ++j) {
        vals[j] = xp[(size_t)j * 4096];
        v[j] = (short)f2bf(vals[j]);
    }
    int h = p >> 6, w = p & 63;
    *(v8s*)(xbp + ((size_t)((b * XP + h + 1) * XP + w + 1)) * CC + g * 8) = v;

    __shared__ float ls[4][8];
    int lane = threadIdx.x & 63, wv = threadIdx.x >> 6;
    #pragma unroll
    for (int j = 0; j < 8; ++j) {
        float s = vals[j];
        #pragma unroll
        for (int off = 32; off > 0; off >>= 1) s += __shfl_down(s, off, 64);
        if (lane == 0) ls[wv][j] = s;
    }
    __syncthreads();
    if (threadIdx.x < 8) {
        float s = ls[0][threadIdx.x] + ls[1][threadIdx.x] + ls[2][threadIdx.x] + ls[3][threadIdx.x];
        atomicAdd(&pooled[b * CC + g * 8 + threadIdx.x], s);
    }
}

// ---------------- kernel 2: fused SE-MLP + softmax + bank mix -> bf16 A [b][o][tap*128+c] ----
__global__ __launch_bounds__(256) void mix_kernel(const float* __restrict__ kernels,
        const float* __restrict__ pooled,
        const float* __restrict__ w1, const float* __restrict__ b1,
        const float* __restrict__ w2, const float* __restrict__ b2,
        unsigned short* __restrict__ wmixb) {
    const int b = blockIdx.y, o = blockIdx.x;
    const int t = threadIdx.x;
    __shared__ float hs[RR];
    __shared__ float lgs[KK];
    __shared__ float attns[KK];
    __shared__ unsigned short ws[KTOT];

    if (t < RR) {
        float acc = b1[t];
        const float* pr = pooled + b * CC;
        const float* wr = w1 + t * CC;
        for (int c = 0; c < CC; ++c) acc += (pr[c] * (1.0f / 4096.0f)) * wr[c];
        hs[t] = fmaxf(acc, 0.f);
    }
    __syncthreads();
    if (t < KK) {
        float a = b2[t];
        #pragma unroll
        for (int r = 0; r < RR; ++r) a += hs[r] * w2[t * RR + r];
        lgs[t] = a;
    }
    __syncthreads();
    if (t == 0) {
        float m = fmaxf(fmaxf(lgs[0], lgs[1]), fmaxf(lgs[2], lgs[3]));
        float e0 = expf(lgs[0] - m), e1 = expf(lgs[1] - m);
        float e2 = expf(lgs[2] - m), e3 = expf(lgs[3] - m);
        float inv = 1.f / (e0 + e1 + e2 + e3);
        attns[0] = e0 * inv; attns[1] = e1 * inv; attns[2] = e2 * inv; attns[3] = e3 * inv;
    }
    __syncthreads();
    float a0 = attns[0], a1 = attns[1], a2 = attns[2], a3 = attns[3];

    const size_t KB = (size_t)OO * KTOT;
    const float* k0 = kernels + (size_t)o * KTOT;
    for (int ii = t; ii < KTOT; ii += 256) {
        int c = ii / 9, tap = ii - c * 9;
        float v = a0 * k0[ii] + a1 * k0[KB + ii] + a2 * k0[2 * KB + ii] + a3 * k0[3 * KB + ii];
        ws[tap * 128 + c] = f2bf(v);
    }
    __syncthreads();
    v8s* wp8 = (v8s*)(wmixb + ((size_t)b * OO + o) * KTOT);
    const v8s* ls8 = (const v8s*)ws;
    for (int ii = t; ii < KTOT / 8; ii += 256) wp8[ii] = ls8[ii];
}

// ---------------- kernel 3: implicit-GEMM conv, m97-style double-buffered LDS ----------------
// grid 512 = 8 XCD * (2 b * 32 ntiles). 256 thr = 4 waves (wm = o-half, wn = row-of-2).
// Per K-step (32 k): A-tile [128 o][32 k] + B-tile [128 p][32 c] staged via global_load_lds.
#define MFMA16(acc, va, vb) \
    asm volatile("v_mfma_f32_16x16x32_bf16 %0, %1, %2, %0" : "+v"(acc) : "v"(va), "v"(vb))

#define STAGE(ks_, buf_) { \
    const int tap_ = (ks_) >> 2; \
    const int dy_ = tap_ / 3, dx_ = tap_ % 3; \
    const int c0_ = ((ks_) & 3) * 32; \
    const unsigned short* sa_ = srcA0 + (ks_) * 32; \
    const unsigned short* sb_ = srcB0 + ((size_t)(dy_ * XP + dx_)) * CC + c0_; \
    gl16(sa_,                     &Ab[buf_][wid * 512]); \
    gl16(sa_ + (size_t)64 * KTOT, &Ab[buf_][(wid + 4) * 512]); \
    gl16(sb_,                     &Bb[buf_][wid * 512]); \
    gl16(sb_ + XP * CC,           &Bb[buf_][(wid + 4) * 512]); \
}

__global__ __launch_bounds__(256, 2) void conv_kernel(
        const unsigned short* __restrict__ xbp,
        const unsigned short* __restrict__ wmixb,
        float* __restrict__ out) {
    __shared__ unsigned short Ab[2][4096];   // [128 o][32 k] bf16, 8KB each
    __shared__ unsigned short Bb[2][4096];   // [128 p][32 c]
    int bid = blockIdx.x;
    int xcd = bid & 7, idx = bid >> 3;
    int b = xcd * 2 + (idx >> 5);
    int nt = idx & 31;
    int t = threadIdx.x;
    int lane = t & 63, wid = t >> 6;
    int wm = wid & 1, wn = wid >> 1;   // wn in {0,1}

    v4f acc[4][4];
    #pragma unroll
    for (int i = 0; i < 4; ++i)
        #pragma unroll
        for (int j = 0; j < 4; ++j) acc[i][j] = (v4f)0.f;

    // staging source bases (per thread): chunk rows = wid*16 + (lane>>2), chunk g = lane&3
    int l4 = lane >> 2, g = lane & 3;
    const unsigned short* srcA0 = wmixb + ((size_t)(b * OO + wid * 16 + l4)) * KTOT + g * 8;
    const unsigned short* srcB0 = xbp + ((size_t)((b * XP + nt * 2) * XP) + wid * 16 + l4) * CC + g * 8;
    // fragment read base (bytes into tile): row = lane&15 (+16*mf), chunk = lane>>4
    int lane_off = (lane & 15) * 64 + (lane >> 4) * 16;

    STAGE(0, 0);
    asm volatile("s_waitcnt vmcnt(0)" ::: "memory");
    __syncthreads();

    #pragma unroll
    for (int ks = 0; ks < NT; ++ks) {
        const int buf_ = ks & 1;
        if (ks < NT - 1) STAGE(ks + 1, buf_ ^ 1);
        v8s af[4], bfv[4];
        const char* abase = (const char*)&Ab[buf_][0] + wm * 4096 + lane_off;
        const char* bbase = (const char*)&Bb[buf_][0] + wn * 4096 + lane_off;
        #pragma unroll
        for (int mf = 0; mf < 4; ++mf) af[mf] = *(const v8s*)(abase + mf * 1024);
        #pragma unroll
        for (int nf = 0; nf < 4; ++nf) bfv[nf] = *(const v8s*)(bbase + nf * 1024);
        #pragma unroll
        for (int mf = 0; mf < 4; ++mf)
            #pragma unroll
            for (int nf = 0; nf < 4; ++nf)
                MFMA16(acc[mf][nf], af[mf], bfv[nf]);
        asm volatile("s_waitcnt vmcnt(0)" ::: "memory");
        __syncthreads();
    }
    asm volatile("s_nop 7\ns_nop 7" ::: );

    // epilogue: C/D layout col = lane&15 (pixel), row = (lane>>4)*4 + jj (o)
    int r = nt * 2 + wn;
    #pragma unroll
    for (int mf = 0; mf < 4; ++mf) {
        int o = wm * 64 + mf * 16 + ((lane >> 4) << 2);
        #pragma unroll
        for (int jj = 0; jj < 4; ++jj) {
            float* op = out + (((size_t)(b * OO + o + jj)) * HH + r) * WW;
            #pragma unroll
            for (int nf = 0; nf < 4; ++nf)
                op[nf * 16 + (lane & 15)] = acc[mf][nf][jj];
        }
    }
}

extern "C" void kernel_launch(void* const* d_in, const int* in_sizes, int n_in,
                              void* d_out, int out_size, void* d_ws, size_t ws_size,
                              hipStream_t stream) {
    const float* x       = (const float*)d_in[0];
    const float* w1      = (const float*)d_in[1];
    const float* b1      = (const float*)d_in[2];
    const float* w2      = (const float*)d_in[3];
    const float* b2      = (const float*)d_in[4];
    const float* kernels = (const float*)d_in[5];
    float* out = (float*)d_out;

    // ws layout: pooled[2048] f32 | xbp[16*66*66*128] bf16 | wmixb[16*128*1152] bf16
    float* pooled = (float*)d_ws;
    unsigned short* xbp   = (unsigned short*)(pooled + BB * CC);
    unsigned short* wmixb = xbp + (size_t)BB * XP * XP * CC;

    hipMemsetAsync(pooled, 0, BB * CC * sizeof(float), stream);
    border_kernel<<<dim3(17, BB), 256, 0, stream>>>(xbp);
    convert_pool_kernel<<<4096, 256, 0, stream>>>(x, xbp, pooled);
    mix_kernel<<<dim3(OO, BB), 256, 0, stream>>>(kernels, pooled, w1, b1, w2, b2, wmixb);
    conv_kernel<<<512, 256, 0, stream>>>(xbp, wmixb, out);
}

// Round 5
// 65.103 us; speedup vs baseline: 5.5184x; 1.0310x over previous
//
#include <hip/hip_runtime.h>

#define BB 16
#define CC 128
#define HH 64
#define WW 64
#define OO 128
#define KK 4
#define RR 32
#define KTOT 1152          // 9 * 128
#define NT 36              // K-steps of 32
#define XP 66              // padded spatial dim

typedef short v8s __attribute__((ext_vector_type(8)));
typedef float v4f __attribute__((ext_vector_type(4)));

__device__ __forceinline__ unsigned short f2bf(float f) {
    unsigned u = __builtin_bit_cast(unsigned, f);
    u += 0x7fffu + ((u >> 16) & 1u);
    return (unsigned short)(u >> 16);
}

// async global->LDS, 16B per lane; LDS dest is wave-uniform base + lane*16
__device__ __forceinline__ void gl16(const unsigned short* g, unsigned short* l) {
    __builtin_amdgcn_global_load_lds(
        (const __attribute__((address_space(1))) unsigned int*)g,
        (__attribute__((address_space(3))) unsigned int*)l, 16, 0, 0);
}

// ---------------- kernel 0: zero halo border of padded xb + zero pooled ----------------
__global__ void border_kernel(unsigned short* __restrict__ xbp, float* __restrict__ pooled) {
    int b = blockIdx.y;
    if (blockIdx.x == 0 && threadIdx.x < CC) pooled[b * CC + threadIdx.x] = 0.f;
    int i = blockIdx.x * 256 + threadIdx.x;   // [0, 4160) cells*16
    if (i >= 4160) return;
    int cell = i >> 4, wi = i & 15;
    int r, c;
    if (cell < 66)       { r = 0;              c = cell; }
    else if (cell < 132) { r = 65;             c = cell - 66; }
    else if (cell < 196) { r = cell - 132 + 1; c = 0; }
    else                 { r = cell - 196 + 1; c = 65; }
    *(v8s*)(xbp + ((size_t)((b * XP + r) * XP + c)) * CC + wi * 8) = (v8s)0;
}

// ---------------- kernel 1: convert fp32 NCHW -> bf16 padded NHWC + fused avg-pool ----------------
__global__ __launch_bounds__(256) void convert_pool_kernel(const float* __restrict__ x,
        unsigned short* __restrict__ xbp, float* __restrict__ pooled) {
    int idx = blockIdx.x * 256 + threadIdx.x;
    int p = idx & 4095;
    int g = (idx >> 12) & 15;
    int b = idx >> 16;
    const float* xp = x + ((size_t)(b * CC + g * 8)) * 4096 + p;
    float vals[8];
    v8s v;
    #pragma unroll
    for (int j = 0; j < 8; ++j) {
        vals[j] = xp[(size_t)j * 4096];
        v[j] = (short)f2bf(vals[j]);
    }
    int h = p >> 6, w = p & 63;
    *(v8s*)(xbp + ((size_t)((b * XP + h + 1) * XP + w + 1)) * CC + g * 8) = v;

    __shared__ float ls[4][8];
    int lane = threadIdx.x & 63, wv = threadIdx.x >> 6;
    #pragma unroll
    for (int j = 0; j < 8; ++j) {
        float s = vals[j];
        #pragma unroll
        for (int off = 32; off > 0; off >>= 1) s += __shfl_down(s, off, 64);
        if (lane == 0) ls[wv][j] = s;
    }
    __syncthreads();
    if (threadIdx.x < 8) {
        float s = ls[0][threadIdx.x] + ls[1][threadIdx.x] + ls[2][threadIdx.x] + ls[3][threadIdx.x];
        atomicAdd(&pooled[b * CC + g * 8 + threadIdx.x], s);
    }
}

// ---------------- kernel 2: fused SE-MLP + softmax + bank mix -> bf16 A [b][o][tap*128+c] ----
__global__ __launch_bounds__(256) void mix_kernel(const float* __restrict__ kernels,
        const float* __restrict__ pooled,
        const float* __restrict__ w1, const float* __restrict__ b1,
        const float* __restrict__ w2, const float* __restrict__ b2,
        unsigned short* __restrict__ wmixb) {
    const int b = blockIdx.y, o = blockIdx.x;
    const int t = threadIdx.x;
    __shared__ float hs[RR];
    __shared__ float lgs[KK];
    __shared__ float attns[KK];
    __shared__ unsigned short ws[KTOT];

    if (t < RR) {
        float acc = b1[t];
        const float* pr = pooled + b * CC;
        const float* wr = w1 + t * CC;
        for (int c = 0; c < CC; ++c) acc += (pr[c] * (1.0f / 4096.0f)) * wr[c];
        hs[t] = fmaxf(acc, 0.f);
    }
    __syncthreads();
    if (t < KK) {
        float a = b2[t];
        #pragma unroll
        for (int r = 0; r < RR; ++r) a += hs[r] * w2[t * RR + r];
        lgs[t] = a;
    }
    __syncthreads();
    if (t == 0) {
        float m = fmaxf(fmaxf(lgs[0], lgs[1]), fmaxf(lgs[2], lgs[3]));
        float e0 = expf(lgs[0] - m), e1 = expf(lgs[1] - m);
        float e2 = expf(lgs[2] - m), e3 = expf(lgs[3] - m);
        float inv = 1.f / (e0 + e1 + e2 + e3);
        attns[0] = e0 * inv; attns[1] = e1 * inv; attns[2] = e2 * inv; attns[3] = e3 * inv;
    }
    __syncthreads();
    float a0 = attns[0], a1 = attns[1], a2 = attns[2], a3 = attns[3];

    const size_t KB = (size_t)OO * KTOT;
    const float* k0 = kernels + (size_t)o * KTOT;
    for (int ii = t; ii < KTOT; ii += 256) {
        int c = ii / 9, tap = ii - c * 9;
        float v = a0 * k0[ii] + a1 * k0[KB + ii] + a2 * k0[2 * KB + ii] + a3 * k0[3 * KB + ii];
        ws[tap * 128 + c] = f2bf(v);
    }
    __syncthreads();
    v8s* wp8 = (v8s*)(wmixb + ((size_t)b * OO + o) * KTOT);
    const v8s* ls8 = (const v8s*)ws;
    for (int ii = t; ii < KTOT / 8; ii += 256) wp8[ii] = ls8[ii];
}

// ---------------- kernel 3: implicit-GEMM conv, m97-style double-buffered LDS ----------------
// grid 512 = 8 XCD * (2 b * 32 ntiles). 256 thr = 4 waves (wm = o-half, wn = row-of-2).
// Per K-step (32 k): A-tile [128 o][32 k] + B-tile [128 p][32 c] staged via global_load_lds.
#define MFMA16(acc, va, vb) \
    asm volatile("v_mfma_f32_16x16x32_bf16 %0, %1, %2, %0" : "+v"(acc) : "v"(va), "v"(vb))

#define STAGE(ks_, buf_) { \
    const int tap_ = (ks_) >> 2; \
    const int dy_ = tap_ / 3, dx_ = tap_ % 3; \
    const int c0_ = ((ks_) & 3) * 32; \
    const unsigned short* sa_ = srcA0 + (ks_) * 32; \
    const unsigned short* sb_ = srcB0 + ((size_t)(dy_ * XP + dx_)) * CC + c0_; \
    gl16(sa_,                     &Ab[buf_][wid * 512]); \
    gl16(sa_ + (size_t)64 * KTOT, &Ab[buf_][(wid + 4) * 512]); \
    gl16(sb_,                     &Bb[buf_][wid * 512]); \
    gl16(sb_ + XP * CC,           &Bb[buf_][(wid + 4) * 512]); \
}

__global__ __launch_bounds__(256, 2) void conv_kernel(
        const unsigned short* __restrict__ xbp,
        const unsigned short* __restrict__ wmixb,
        float* __restrict__ out) {
    __shared__ unsigned short Ab[2][4096];   // [128 o][32 k] bf16, 8KB each
    __shared__ unsigned short Bb[2][4096];   // [128 p][32 c]
    int bid = blockIdx.x;
    int xcd = bid & 7, idx = bid >> 3;
    int b = xcd * 2 + (idx >> 5);
    int nt = idx & 31;
    int t = threadIdx.x;
    int lane = t & 63, wid = t >> 6;
    int wm = wid & 1, wn = wid >> 1;   // wn in {0,1}

    v4f acc[4][4];
    #pragma unroll
    for (int i = 0; i < 4; ++i)
        #pragma unroll
        for (int j = 0; j < 4; ++j) acc[i][j] = (v4f)0.f;

    // staging source bases (per thread): chunk rows = wid*16 + (lane>>2), chunk g = lane&3
    int l4 = lane >> 2, g = lane & 3;
    const unsigned short* srcA0 = wmixb + ((size_t)(b * OO + wid * 16 + l4)) * KTOT + g * 8;
    const unsigned short* srcB0 = xbp + ((size_t)((b * XP + nt * 2) * XP) + wid * 16 + l4) * CC + g * 8;
    // fragment read base (bytes into tile): row = lane&15 (+16*mf), chunk = lane>>4
    int lane_off = (lane & 15) * 64 + (lane >> 4) * 16;

    STAGE(0, 0);
    asm volatile("s_waitcnt vmcnt(0)" ::: "memory");
    __syncthreads();

    #pragma unroll
    for (int ks = 0; ks < NT; ++ks) {
        const int buf_ = ks & 1;
        if (ks < NT - 1) STAGE(ks + 1, buf_ ^ 1);
        v8s af[4], bfv[4];
        const char* abase = (const char*)&Ab[buf_][0] + wm * 4096 + lane_off;
        const char* bbase = (const char*)&Bb[buf_][0] + wn * 4096 + lane_off;
        #pragma unroll
        for (int mf = 0; mf < 4; ++mf) af[mf] = *(const v8s*)(abase + mf * 1024);
        #pragma unroll
        for (int nf = 0; nf < 4; ++nf) bfv[nf] = *(const v8s*)(bbase + nf * 1024);
        #pragma unroll
        for (int mf = 0; mf < 4; ++mf)
            #pragma unroll
            for (int nf = 0; nf < 4; ++nf)
                MFMA16(acc[mf][nf], af[mf], bfv[nf]);
        asm volatile("s_waitcnt vmcnt(0)" ::: "memory");
        __syncthreads();
    }
    asm volatile("s_nop 7\ns_nop 7" ::: );

    // epilogue: C/D layout col = lane&15 (pixel), row = (lane>>4)*4 + jj (o)
    int r = nt * 2 + wn;
    #pragma unroll
    for (int mf = 0; mf < 4; ++mf) {
        int o = wm * 64 + mf * 16 + ((lane >> 4) << 2);
        #pragma unroll
        for (int jj = 0; jj < 4; ++jj) {
            float* op = out + (((size_t)(b * OO + o + jj)) * HH + r) * WW;
            #pragma unroll
            for (int nf = 0; nf < 4; ++nf)
                op[nf * 16 + (lane & 15)] = acc[mf][nf][jj];
        }
    }
}

extern "C" void kernel_launch(void* const* d_in, const int* in_sizes, int n_in,
                              void* d_out, int out_size, void* d_ws, size_t ws_size,
                              hipStream_t stream) {
    const float* x       = (const float*)d_in[0];
    const float* w1      = (const float*)d_in[1];
    const float* b1      = (const float*)d_in[2];
    const float* w2      = (const float*)d_in[3];
    const float* b2      = (const float*)d_in[4];
    const float* kernels = (const float*)d_in[5];
    float* out = (float*)d_out;

    // ws layout: pooled[2048] f32 | xbp[16*66*66*128] bf16 | wmixb[16*128*1152] bf16
    float* pooled = (float*)d_ws;
    unsigned short* xbp   = (unsigned short*)(pooled + BB * CC);
    unsigned short* wmixb = xbp + (size_t)BB * XP * XP * CC;

    border_kernel<<<dim3(17, BB), 256, 0, stream>>>(xbp, pooled);
    convert_pool_kernel<<<4096, 256, 0, stream>>>(x, xbp, pooled);
    mix_kernel<<<dim3(OO, BB), 256, 0, stream>>>(kernels, pooled, w1, b1, w2, b2, wmixb);
    conv_kernel<<<512, 256, 0, stream>>>(xbp, wmixb, out);
}

// Round 6
// 58.868 us; speedup vs baseline: 6.1029x; 1.1059x over previous
//
#include <hip/hip_runtime.h>

#define BB 16
#define CC 128
#define HH 64
#define WW 64
#define OO 128
#define KK 4
#define RR 32
#define KTOT 1152          // 9 * 128
#define NT 36              // K-steps of 32
#define XP 66              // padded spatial dim

typedef short v8s __attribute__((ext_vector_type(8)));
typedef float v4f __attribute__((ext_vector_type(4)));

__device__ __forceinline__ unsigned short f2bf(float f) {
    unsigned u = __builtin_bit_cast(unsigned, f);
    u += 0x7fffu + ((u >> 16) & 1u);
    return (unsigned short)(u >> 16);
}

// async global->LDS, 16B per lane; LDS dest is wave-uniform base + lane*16
__device__ __forceinline__ void gl16(const unsigned short* g, unsigned short* l) {
    __builtin_amdgcn_global_load_lds(
        (const __attribute__((address_space(1))) unsigned int*)g,
        (__attribute__((address_space(3))) unsigned int*)l, 16, 0, 0);
}

// ---------------- kernel 1: convert fp32 NCHW -> bf16 padded NHWC + halo zero + pool partials ----
// grid 4096 = (b:4bits)(g:4bits)(pxblk:4bits), 256 thr. No atomics: per-block partial sums.
__global__ __launch_bounds__(256) void convert_pool_kernel(const float* __restrict__ x,
        unsigned short* __restrict__ xbp, float* __restrict__ part) {
    int bid = blockIdx.x;
    int t = threadIdx.x;
    int p = (bid & 15) * 256 + t;
    int g = (bid >> 4) & 15;
    int b = bid >> 8;
    const float* xp = x + ((size_t)(b * CC + g * 8)) * 4096 + p;
    float vals[8];
    v8s v;
    #pragma unroll
    for (int j = 0; j < 8; ++j) {
        vals[j] = xp[(size_t)j * 4096];
        v[j] = (short)f2bf(vals[j]);
    }
    int h = p >> 6, w = p & 63;
    unsigned short* xb_b = xbp + (size_t)b * XP * XP * CC + g * 8;
    *(v8s*)(xb_b + (size_t)((h + 1) * XP + w + 1) * CC) = v;

    // halo zeros (edge threads only)
    v8s z = (v8s)0;
    if (w == 0)  *(v8s*)(xb_b + (size_t)((h + 1) * XP) * CC) = z;
    if (w == 63) *(v8s*)(xb_b + (size_t)((h + 1) * XP + 65) * CC) = z;
    if (h == 0)  *(v8s*)(xb_b + (size_t)(w + 1) * CC) = z;
    if (h == 63) *(v8s*)(xb_b + (size_t)(65 * XP + w + 1) * CC) = z;
    if (h == 0 && w == 0)   *(v8s*)(xb_b + 0) = z;
    if (h == 0 && w == 63)  *(v8s*)(xb_b + (size_t)65 * CC) = z;
    if (h == 63 && w == 0)  *(v8s*)(xb_b + (size_t)(65 * XP) * CC) = z;
    if (h == 63 && w == 63) *(v8s*)(xb_b + (size_t)(65 * XP + 65) * CC) = z;

    // pool partials: sum over this block's 256 px for 8 channels
    __shared__ float ls[4][8];
    int lane = t & 63, wv = t >> 6;
    #pragma unroll
    for (int j = 0; j < 8; ++j) {
        float s = vals[j];
        #pragma unroll
        for (int off = 32; off > 0; off >>= 1) s += __shfl_down(s, off, 64);
        if (lane == 0) ls[wv][j] = s;
    }
    __syncthreads();
    if (t < 8) {
        float s = ls[0][t] + ls[1][t] + ls[2][t] + ls[3][t];
        // part[b][g][pxblk][j]
        part[(((b * 16 + g) * 16) + (bid & 15)) * 8 + t] = s;
    }
}

// ---------------- kernel 2: pool-reduce + SE-MLP + softmax + bank mix -> bf16 A [b][o][tap*128+c] ----
__global__ __launch_bounds__(256) void mix_kernel(const float* __restrict__ kernels,
        const float* __restrict__ part,
        const float* __restrict__ w1, const float* __restrict__ b1,
        const float* __restrict__ w2, const float* __restrict__ b2,
        unsigned short* __restrict__ wmixb) {
    const int b = blockIdx.y, o = blockIdx.x;
    const int t = threadIdx.x;
    __shared__ float pooled_sh[CC];
    __shared__ float hs[RR];
    __shared__ float lgs[KK];
    __shared__ float attns[KK];
    __shared__ unsigned short ws[KTOT];

    if (t < CC) {
        const float* pp = part + ((b * 16 + (t >> 3)) * 16) * 8 + (t & 7);
        float s = 0.f;
        #pragma unroll
        for (int pb = 0; pb < 16; ++pb) s += pp[pb * 8];
        pooled_sh[t] = s * (1.0f / 4096.0f);
    }
    __syncthreads();
    if (t < RR) {
        float acc = b1[t];
        const float* wr = w1 + t * CC;
        for (int c = 0; c < CC; ++c) acc += pooled_sh[c] * wr[c];
        hs[t] = fmaxf(acc, 0.f);
    }
    __syncthreads();
    if (t < KK) {
        float a = b2[t];
        #pragma unroll
        for (int r = 0; r < RR; ++r) a += hs[r] * w2[t * RR + r];
        lgs[t] = a;
    }
    __syncthreads();
    if (t == 0) {
        float m = fmaxf(fmaxf(lgs[0], lgs[1]), fmaxf(lgs[2], lgs[3]));
        float e0 = expf(lgs[0] - m), e1 = expf(lgs[1] - m);
        float e2 = expf(lgs[2] - m), e3 = expf(lgs[3] - m);
        float inv = 1.f / (e0 + e1 + e2 + e3);
        attns[0] = e0 * inv; attns[1] = e1 * inv; attns[2] = e2 * inv; attns[3] = e3 * inv;
    }
    __syncthreads();
    float a0 = attns[0], a1 = attns[1], a2 = attns[2], a3 = attns[3];

    const size_t KB = (size_t)OO * KTOT;
    const float* k0 = kernels + (size_t)o * KTOT;
    for (int ii = t; ii < KTOT; ii += 256) {
        int c = ii / 9, tap = ii - c * 9;
        float v = a0 * k0[ii] + a1 * k0[KB + ii] + a2 * k0[2 * KB + ii] + a3 * k0[3 * KB + ii];
        ws[tap * 128 + c] = f2bf(v);
    }
    __syncthreads();
    v8s* wp8 = (v8s*)(wmixb + ((size_t)b * OO + o) * KTOT);
    const v8s* ls8 = (const v8s*)ws;
    for (int ii = t; ii < KTOT / 8; ii += 256) wp8[ii] = ls8[ii];
}

// ---------------- kernel 3: implicit-GEMM conv, 3-deep counted-vmcnt pipeline ----------------
// grid 512 = 8 XCD * (2 b * 32 ntiles). 256 thr = 4 waves (wm = o-half, wn = row-of-2).
// Per K-step (32 k): A-tile [128 o][32 k] + B-tile [128 p][32 c] staged via global_load_lds.
// Counted vmcnt: tile k+1's loads stay in flight across the barrier (T3/T4).
#define MFMA16(acc, va, vb) \
    asm volatile("v_mfma_f32_16x16x32_bf16 %0, %1, %2, %0" : "+v"(acc) : "v"(va), "v"(vb))

#define STAGE(ks_, buf_) { \
    const int tap_ = (ks_) >> 2; \
    const int dy_ = tap_ / 3, dx_ = tap_ % 3; \
    const int c0_ = ((ks_) & 3) * 32; \
    const unsigned short* sa_ = srcA0 + (ks_) * 32; \
    const unsigned short* sb_ = srcB0 + ((size_t)(dy_ * XP + dx_)) * CC + c0_; \
    gl16(sa_,                     &Ab[buf_][wid * 512]); \
    gl16(sa_ + (size_t)64 * KTOT, &Ab[buf_][(wid + 4) * 512]); \
    gl16(sb_,                     &Bb[buf_][wid * 512]); \
    gl16(sb_ + XP * CC,           &Bb[buf_][(wid + 4) * 512]); \
}

__global__ __launch_bounds__(256, 2) void conv_kernel(
        const unsigned short* __restrict__ xbp,
        const unsigned short* __restrict__ wmixb,
        float* __restrict__ out) {
    __shared__ unsigned short Ab[3][4096];   // [128 o][32 k] bf16, 8KB each
    __shared__ unsigned short Bb[3][4096];   // [128 p][32 c]
    int bid = blockIdx.x;
    int xcd = bid & 7, idx = bid >> 3;
    int b = xcd * 2 + (idx >> 5);
    int nt = idx & 31;
    int t = threadIdx.x;
    int lane = t & 63, wid = t >> 6;
    int wm = wid & 1, wn = wid >> 1;   // wn in {0,1}

    v4f acc[4][4];
    #pragma unroll
    for (int i = 0; i < 4; ++i)
        #pragma unroll
        for (int j = 0; j < 4; ++j) acc[i][j] = (v4f)0.f;

    // staging source bases (per thread): chunk rows = wid*16 + (lane>>2), chunk g = lane&3
    int l4 = lane >> 2, g = lane & 3;
    const unsigned short* srcA0 = wmixb + ((size_t)(b * OO + wid * 16 + l4)) * KTOT + g * 8;
    const unsigned short* srcB0 = xbp + ((size_t)((b * XP + nt * 2) * XP) + wid * 16 + l4) * CC + g * 8;
    // fragment read base (bytes into tile): row = lane&15 (+16*mf), chunk = lane>>4
    int lane_off = (lane & 15) * 64 + (lane >> 4) * 16;

    STAGE(0, 0);
    STAGE(1, 1);

    #pragma unroll
    for (int ks = 0; ks < NT; ++ks) {
        if (ks == NT - 1) {
            asm volatile("s_waitcnt vmcnt(0)" ::: "memory");
        } else {
            asm volatile("s_waitcnt vmcnt(4)" ::: "memory");
        }
        __builtin_amdgcn_s_barrier();
        if (ks + 2 < NT) STAGE(ks + 2, (ks + 2) % 3);
        const int buf_ = ks % 3;
        v8s af[4], bfv[4];
        const char* abase = (const char*)&Ab[buf_][0] + wm * 4096 + lane_off;
        const char* bbase = (const char*)&Bb[buf_][0] + wn * 4096 + lane_off;
        #pragma unroll
        for (int mf = 0; mf < 4; ++mf) af[mf] = *(const v8s*)(abase + mf * 1024);
        #pragma unroll
        for (int nf = 0; nf < 4; ++nf) bfv[nf] = *(const v8s*)(bbase + nf * 1024);
        #pragma unroll
        for (int mf = 0; mf < 4; ++mf)
            #pragma unroll
            for (int nf = 0; nf < 4; ++nf)
                MFMA16(acc[mf][nf], af[mf], bfv[nf]);
    }
    asm volatile("s_nop 7\ns_nop 7" ::: );

    // epilogue: C/D layout col = lane&15 (pixel), row = (lane>>4)*4 + jj (o)
    int r = nt * 2 + wn;
    #pragma unroll
    for (int mf = 0; mf < 4; ++mf) {
        int o = wm * 64 + mf * 16 + ((lane >> 4) << 2);
        #pragma unroll
        for (int jj = 0; jj < 4; ++jj) {
            float* op = out + (((size_t)(b * OO + o + jj)) * HH + r) * WW;
            #pragma unroll
            for (int nf = 0; nf < 4; ++nf)
                op[nf * 16 + (lane & 15)] = acc[mf][nf][jj];
        }
    }
}

extern "C" void kernel_launch(void* const* d_in, const int* in_sizes, int n_in,
                              void* d_out, int out_size, void* d_ws, size_t ws_size,
                              hipStream_t stream) {
    const float* x       = (const float*)d_in[0];
    const float* w1      = (const float*)d_in[1];
    const float* b1      = (const float*)d_in[2];
    const float* w2      = (const float*)d_in[3];
    const float* b2      = (const float*)d_in[4];
    const float* kernels = (const float*)d_in[5];
    float* out = (float*)d_out;

    // ws layout: part[16*16*16*8] f32 | xbp[16*66*66*128] bf16 | wmixb[16*128*1152] bf16
    float* part = (float*)d_ws;
    unsigned short* xbp   = (unsigned short*)(part + 16 * 16 * 16 * 8);
    unsigned short* wmixb = xbp + (size_t)BB * XP * XP * CC;

    convert_pool_kernel<<<4096, 256, 0, stream>>>(x, xbp, part);
    mix_kernel<<<dim3(OO, BB), 256, 0, stream>>>(kernels, part, w1, b1, w2, b2, wmixb);
    conv_kernel<<<512, 256, 0, stream>>>(xbp, wmixb, out);
}